// Round 1
// baseline (2112.447 us; speedup 1.0000x reference)
//
#include <hip/hip_runtime.h>

#define N_NODES 100000
#define N_EDGES 1600000
#define DIM_IN 128
#define DIM_HID 128
#define DIM_OUT 64

// ---------------------------------------------------------------------------
// Scatter-add: one thread per (edge, feature-channel). feat is [N,128].
// sum[dst] += feat[src]; deg[dst] += 1 (only when do_deg, channel 0).
// ---------------------------------------------------------------------------
__global__ void scatter_kernel(const float* __restrict__ feat,
                               const int* __restrict__ src,
                               const int* __restrict__ dst,
                               float* __restrict__ sum,
                               float* __restrict__ deg,
                               int do_deg) {
    long long idx = (long long)blockIdx.x * blockDim.x + threadIdx.x;
    const long long total = (long long)N_EDGES * 128;
    if (idx >= total) return;
    int e = (int)(idx >> 7);
    int d = (int)(idx & 127);
    int s = src[e];
    int t = dst[e];
    atomicAdd(&sum[(long long)t * 128 + d], feat[(long long)s * 128 + d]);
    if (do_deg && d == 0) atomicAdd(&deg[t], 1.0f);
}

// ---------------------------------------------------------------------------
// Layer-1 epilogue: h[i,j] = relu( mean[i,:] @ W1_l[:,j] + x[i,:] @ W1_r[:,j] + b1[j] )
// One 128-thread block per node; x and mean staged in LDS.
// W is row-major [128,128]: W[k*128 + j] — coalesced across j (threadIdx).
// ---------------------------------------------------------------------------
__global__ void gemm1_kernel(const float* __restrict__ x,
                             const float* __restrict__ sum,
                             const float* __restrict__ deg,
                             const float* __restrict__ Wl,
                             const float* __restrict__ Wr,
                             const float* __restrict__ b,
                             float* __restrict__ h) {
    __shared__ float xs[128];
    __shared__ float ms[128];
    int node = blockIdx.x;
    int j = threadIdx.x;
    float inv = 1.0f / fmaxf(deg[node], 1.0f);
    xs[j] = x[(long long)node * 128 + j];
    ms[j] = sum[(long long)node * 128 + j] * inv;
    __syncthreads();
    float acc = b[j];
#pragma unroll 8
    for (int k = 0; k < 128; k++) {
        acc += ms[k] * Wl[k * 128 + j] + xs[k] * Wr[k * 128 + j];
    }
    h[(long long)node * 128 + j] = fmaxf(acc, 0.0f);
}

// ---------------------------------------------------------------------------
// Layer-2 epilogue: out[i,j] = mean2[i,:] @ W2_l[:,j] + h[i,:] @ W2_r[:,j] + b2[j]
// One 64-thread block (one wave) per node. W2 is [128,64] row-major.
// ---------------------------------------------------------------------------
__global__ void gemm2_kernel(const float* __restrict__ h,
                             const float* __restrict__ sum,
                             const float* __restrict__ deg,
                             const float* __restrict__ Wl,
                             const float* __restrict__ Wr,
                             const float* __restrict__ b,
                             float* __restrict__ out) {
    __shared__ float hs[128];
    __shared__ float ms[128];
    int node = blockIdx.x;
    int j = threadIdx.x;  // 0..63
    float inv = 1.0f / fmaxf(deg[node], 1.0f);
    hs[j]      = h[(long long)node * 128 + j];
    hs[j + 64] = h[(long long)node * 128 + j + 64];
    ms[j]      = sum[(long long)node * 128 + j] * inv;
    ms[j + 64] = sum[(long long)node * 128 + j + 64] * inv;
    __syncthreads();
    float acc = b[j];
#pragma unroll 8
    for (int k = 0; k < 128; k++) {
        acc += ms[k] * Wl[k * 64 + j] + hs[k] * Wr[k * 64 + j];
    }
    out[(long long)node * 64 + j] = acc;
}

extern "C" void kernel_launch(void* const* d_in, const int* in_sizes, int n_in,
                              void* d_out, int out_size, void* d_ws, size_t ws_size,
                              hipStream_t stream) {
    const float* x   = (const float*)d_in[0];
    const int*   ei  = (const int*)d_in[1];   // [2, E] int32 (JAX x64 disabled)
    const float* W1l = (const float*)d_in[2];
    const float* W1r = (const float*)d_in[3];
    const float* b1  = (const float*)d_in[4];
    const float* W2l = (const float*)d_in[5];
    const float* W2r = (const float*)d_in[6];
    const float* b2  = (const float*)d_in[7];

    const int* src = ei;            // edge_index[0]
    const int* dst = ei + N_EDGES;  // edge_index[1]

    // Workspace layout (floats):
    //   deg : N_NODES (padded to 100096)
    //   sum : N_NODES*128   (reused for both layers)
    //   h   : N_NODES*128
    float* ws  = (float*)d_ws;
    float* deg = ws;
    float* sum = ws + 100096;
    float* h   = sum + (long long)N_NODES * 128;

    // Zero deg + sum (contiguous).
    hipMemsetAsync(deg, 0, (100096 + (size_t)N_NODES * 128) * sizeof(float), stream);

    const long long scatter_threads = (long long)N_EDGES * 128;
    const int scatter_blocks = (int)((scatter_threads + 255) / 256);

    // Layer 1
    scatter_kernel<<<scatter_blocks, 256, 0, stream>>>(x, src, dst, sum, deg, 1);
    gemm1_kernel<<<N_NODES, 128, 0, stream>>>(x, sum, deg, W1l, W1r, b1, h);

    // Layer 2
    hipMemsetAsync(sum, 0, (size_t)N_NODES * 128 * sizeof(float), stream);
    scatter_kernel<<<scatter_blocks, 256, 0, stream>>>(h, src, dst, sum, deg, 0);
    gemm2_kernel<<<N_NODES, 64, 0, stream>>>(h, sum, deg, W2l, W2r, b2, (float*)d_out);
}

// Round 2
// 813.905 us; speedup vs baseline: 2.5954x; 2.5954x over previous
//
#include <hip/hip_runtime.h>

#define NN 100000
#define NE 1600000

// Workspace layout, in 4-byte element units (all 16B-aligned):
#define OFF_DEGCNT 0
#define OFF_ROWPTR 100352
#define OFF_BSUM   200704
#define OFF_ES     201728
#define OFF_MEAN   1801728
#define OFF_H      (1801728 + 12800000)
// total = 27,401,728 * 4B = 109.6 MB

#define SCAN_BLOCKS 98  // ceil(100000/1024)

// ---------------------------------------------------------------------------
// CSR build step 1: in-degree histogram (int atomics, L2-resident counters)
// ---------------------------------------------------------------------------
__global__ void hist_kernel(const int* __restrict__ dst, int* __restrict__ deg_cnt) {
    int e = blockIdx.x * 256 + threadIdx.x;
    if (e < NE) atomicAdd(&deg_cnt[dst[e]], 1);
}

// ---------------------------------------------------------------------------
// CSR build step 2: exclusive scan of deg_cnt -> row_ptr (3 kernels)
// ---------------------------------------------------------------------------
__global__ void scan1_kernel(const int* __restrict__ deg_cnt,
                             int* __restrict__ row_ptr,
                             int* __restrict__ bsum) {
    __shared__ int s[256];
    int t = threadIdx.x, b = blockIdx.x;
    int base = b * 1024 + t * 4;
    int v0 = (base + 0 < NN) ? deg_cnt[base + 0] : 0;
    int v1 = (base + 1 < NN) ? deg_cnt[base + 1] : 0;
    int v2 = (base + 2 < NN) ? deg_cnt[base + 2] : 0;
    int v3 = (base + 3 < NN) ? deg_cnt[base + 3] : 0;
    s[t] = v0 + v1 + v2 + v3;
    __syncthreads();
    for (int off = 1; off < 256; off <<= 1) {
        int add = (t >= off) ? s[t - off] : 0;
        __syncthreads();
        s[t] += add;
        __syncthreads();
    }
    int excl = (t == 0) ? 0 : s[t - 1];
    if (base + 0 < NN) row_ptr[base + 0] = excl;
    if (base + 1 < NN) row_ptr[base + 1] = excl + v0;
    if (base + 2 < NN) row_ptr[base + 2] = excl + v0 + v1;
    if (base + 3 < NN) row_ptr[base + 3] = excl + v0 + v1 + v2;
    if (t == 255) bsum[b] = s[255];
}

__global__ void scan2_kernel(int* __restrict__ bsum) {
    __shared__ int s[128];
    int t = threadIdx.x;
    s[t] = (t < SCAN_BLOCKS) ? bsum[t] : 0;
    __syncthreads();
    for (int off = 1; off < 128; off <<= 1) {
        int add = (t >= off) ? s[t - off] : 0;
        __syncthreads();
        s[t] += add;
        __syncthreads();
    }
    if (t < SCAN_BLOCKS) bsum[t] = (t == 0) ? 0 : s[t - 1];
}

__global__ void scan3_kernel(int* __restrict__ row_ptr, const int* __restrict__ bsum) {
    int t = threadIdx.x, b = blockIdx.x;
    int base = b * 1024 + t * 4;
    int add = bsum[b];
#pragma unroll
    for (int i = 0; i < 4; ++i)
        if (base + i < NN) row_ptr[base + i] += add;
}

// ---------------------------------------------------------------------------
// CSR build step 3: bucket edges by dst. Uses row_ptr itself as the cursor:
// after this kernel, row_ptr[i] == end offset of bucket i (start = row_ptr[i-1]).
// ---------------------------------------------------------------------------
__global__ void bucket_kernel(const int* __restrict__ src, const int* __restrict__ dst,
                              int* __restrict__ row_ptr, int* __restrict__ es) {
    int e = blockIdx.x * 256 + threadIdx.x;
    if (e >= NE) return;
    int pos = atomicAdd(&row_ptr[dst[e]], 1);
    es[pos] = src[e];
}

// ---------------------------------------------------------------------------
// Aggregation: one wave per node, lane l owns channels {2l, 2l+1}.
// Each edge = one coalesced 512B row gather (L3-resident). Writes mean directly.
// row_end[i] = end of bucket i; start = row_end[i-1] (0 for i==0).
// ---------------------------------------------------------------------------
__global__ __launch_bounds__(256) void agg_kernel(const float* __restrict__ feat,
                                                  const int* __restrict__ row_end,
                                                  const int* __restrict__ es,
                                                  float* __restrict__ mean) {
    int w = threadIdx.x >> 6;
    int l = threadIdx.x & 63;
    int node = blockIdx.x * 4 + w;
    int start = (node == 0) ? 0 : row_end[node - 1];
    int end = row_end[node];
    int c = 2 * l;
    float ax = 0.0f, ay = 0.0f;
    for (int e = start; e < end; ++e) {
        int s = es[e];
        const float2 v = *(const float2*)&feat[(long long)s * 128 + c];
        ax += v.x;
        ay += v.y;
    }
    float inv = 1.0f / fmaxf((float)(end - start), 1.0f);
    float2 o;
    o.x = ax * inv;
    o.y = ay * inv;
    *(float2*)&mean[(long long)node * 128 + c] = o;
}

// ---------------------------------------------------------------------------
// GEMM layer 1: h = relu(mean @ Wl + x @ Wr + b), [100k,128]x[128,128].
// Block = 256 thr (4 waves), chunk = 32 nodes staged in LDS.
// Wave w -> nodes 8w..8w+7 (feat reads are wave-uniform LDS broadcasts).
// Lane l -> channels {2l, 2l+1}. W streamed from global (L1-shared by block).
// Thread tile: 8 nodes x 2 ch x 4 k per iter = 128 fmac.
// ---------------------------------------------------------------------------
__global__ __launch_bounds__(256) void gemm1_kernel(const float* __restrict__ mean,
                                                    const float* __restrict__ x,
                                                    const float* __restrict__ Wl,
                                                    const float* __restrict__ Wr,
                                                    const float* __restrict__ b,
                                                    float* __restrict__ h) {
    __shared__ float ms[32 * 128];
    __shared__ float xs[32 * 128];
    int t = threadIdx.x;
    long long node0 = (long long)blockIdx.x * 32;
    const float4* mg = (const float4*)(mean + node0 * 128);
    const float4* xg = (const float4*)(x + node0 * 128);
    float4* msv = (float4*)ms;
    float4* xsv = (float4*)xs;
#pragma unroll
    for (int i = 0; i < 4; ++i) {
        msv[t + 256 * i] = mg[t + 256 * i];
        xsv[t + 256 * i] = xg[t + 256 * i];
    }
    __syncthreads();

    int w = t >> 6;
    int l = t & 63;
    int nbase = w * 8;
    int c = 2 * l;
    float2 bias = *(const float2*)&b[c];
    float acc0[8], acc1[8];
#pragma unroll
    for (int n = 0; n < 8; ++n) { acc0[n] = bias.x; acc1[n] = bias.y; }

    for (int k4 = 0; k4 < 32; ++k4) {
        float2 wl[4], wr[4];
#pragma unroll
        for (int kk = 0; kk < 4; ++kk) {
            wl[kk] = *(const float2*)&Wl[(4 * k4 + kk) * 128 + c];
            wr[kk] = *(const float2*)&Wr[(4 * k4 + kk) * 128 + c];
        }
#pragma unroll
        for (int n = 0; n < 8; ++n) {
            const float4 mv = *(const float4*)&ms[(nbase + n) * 128 + 4 * k4];
            const float4 xv = *(const float4*)&xs[(nbase + n) * 128 + 4 * k4];
            acc0[n] += mv.x * wl[0].x + mv.y * wl[1].x + mv.z * wl[2].x + mv.w * wl[3].x
                     + xv.x * wr[0].x + xv.y * wr[1].x + xv.z * wr[2].x + xv.w * wr[3].x;
            acc1[n] += mv.x * wl[0].y + mv.y * wl[1].y + mv.z * wl[2].y + mv.w * wl[3].y
                     + xv.x * wr[0].y + xv.y * wr[1].y + xv.z * wr[2].y + xv.w * wr[3].y;
        }
    }
#pragma unroll
    for (int n = 0; n < 8; ++n) {
        float2 o;
        o.x = fmaxf(acc0[n], 0.0f);
        o.y = fmaxf(acc1[n], 0.0f);
        *(float2*)&h[(node0 + nbase + n) * 128 + c] = o;
    }
}

// ---------------------------------------------------------------------------
// GEMM layer 2: out = mean2 @ Wl + h @ Wr + b, [100k,128]x[128,64].
// Same structure; lane l -> channel l (64 out channels), W loads are scalar.
// ---------------------------------------------------------------------------
__global__ __launch_bounds__(256) void gemm2_kernel(const float* __restrict__ mean,
                                                    const float* __restrict__ hin,
                                                    const float* __restrict__ Wl,
                                                    const float* __restrict__ Wr,
                                                    const float* __restrict__ b,
                                                    float* __restrict__ out) {
    __shared__ float ms[32 * 128];
    __shared__ float hs[32 * 128];
    int t = threadIdx.x;
    long long node0 = (long long)blockIdx.x * 32;
    const float4* mg = (const float4*)(mean + node0 * 128);
    const float4* hg = (const float4*)(hin + node0 * 128);
    float4* msv = (float4*)ms;
    float4* hsv = (float4*)hs;
#pragma unroll
    for (int i = 0; i < 4; ++i) {
        msv[t + 256 * i] = mg[t + 256 * i];
        hsv[t + 256 * i] = hg[t + 256 * i];
    }
    __syncthreads();

    int w = t >> 6;
    int l = t & 63;
    int nbase = w * 8;
    float acc[8];
    float bias = b[l];
#pragma unroll
    for (int n = 0; n < 8; ++n) acc[n] = bias;

    for (int k4 = 0; k4 < 32; ++k4) {
        float wl[4], wr[4];
#pragma unroll
        for (int kk = 0; kk < 4; ++kk) {
            wl[kk] = Wl[(4 * k4 + kk) * 64 + l];
            wr[kk] = Wr[(4 * k4 + kk) * 64 + l];
        }
#pragma unroll
        for (int n = 0; n < 8; ++n) {
            const float4 mv = *(const float4*)&ms[(nbase + n) * 128 + 4 * k4];
            const float4 hv = *(const float4*)&hs[(nbase + n) * 128 + 4 * k4];
            acc[n] += mv.x * wl[0] + mv.y * wl[1] + mv.z * wl[2] + mv.w * wl[3]
                    + hv.x * wr[0] + hv.y * wr[1] + hv.z * wr[2] + hv.w * wr[3];
        }
    }
#pragma unroll
    for (int n = 0; n < 8; ++n)
        out[(node0 + nbase + n) * 64 + l] = acc[n];
}

extern "C" void kernel_launch(void* const* d_in, const int* in_sizes, int n_in,
                              void* d_out, int out_size, void* d_ws, size_t ws_size,
                              hipStream_t stream) {
    const float* x   = (const float*)d_in[0];
    const int*   ei  = (const int*)d_in[1];
    const float* W1l = (const float*)d_in[2];
    const float* W1r = (const float*)d_in[3];
    const float* b1  = (const float*)d_in[4];
    const float* W2l = (const float*)d_in[5];
    const float* W2r = (const float*)d_in[6];
    const float* b2  = (const float*)d_in[7];

    const int* src = ei;
    const int* dst = ei + NE;

    int*   ws_i    = (int*)d_ws;
    int*   deg_cnt = ws_i + OFF_DEGCNT;
    int*   row_ptr = ws_i + OFF_ROWPTR;
    int*   bsum    = ws_i + OFF_BSUM;
    int*   es      = ws_i + OFF_ES;
    float* mean    = (float*)ws_i + OFF_MEAN;
    float* h       = (float*)ws_i + OFF_H;

    // 1. CSR build
    hipMemsetAsync(deg_cnt, 0, 100352 * sizeof(int), stream);
    hist_kernel<<<(NE + 255) / 256, 256, 0, stream>>>(dst, deg_cnt);
    scan1_kernel<<<SCAN_BLOCKS, 256, 0, stream>>>(deg_cnt, row_ptr, bsum);
    scan2_kernel<<<1, 128, 0, stream>>>(bsum);
    scan3_kernel<<<SCAN_BLOCKS, 256, 0, stream>>>(row_ptr, bsum);
    bucket_kernel<<<(NE + 255) / 256, 256, 0, stream>>>(src, dst, row_ptr, es);
    // row_ptr[i] now holds END of bucket i.

    // 2. Layer 1: aggregate x -> mean, then h = relu(mean@W1l + x@W1r + b1)
    agg_kernel<<<NN / 4, 256, 0, stream>>>(x, row_ptr, es, mean);
    gemm1_kernel<<<NN / 32, 256, 0, stream>>>(mean, x, W1l, W1r, b1, h);

    // 3. Layer 2: aggregate h -> mean, then out = mean@W2l + h@W2r + b2
    agg_kernel<<<NN / 4, 256, 0, stream>>>(h, row_ptr, es, mean);
    gemm2_kernel<<<NN / 32, 256, 0, stream>>>(mean, h, W2l, W2r, b2, (float*)d_out);
}

// Round 3
// 620.769 us; speedup vs baseline: 3.4029x; 1.3111x over previous
//
#include <hip/hip_runtime.h>

#define NN 100000
#define NE 1600000

// Workspace layout in 4-byte units (total 27,401,728 * 4B = 109.6 MB):
#define OFF_DEGCNT 0
#define OFF_ROWPTR 100352
#define OFF_BSUM   200704
#define OFF_ES     201728
#define OFF_XB     1801728          // x as bf16 [NN,128] (25.6MB); pb [NN,64] bf16 aliases (dead after agg1 / born in gemm1)
#define OFF_MEAN   8201728          // mean1 fp32 [NN,128] (51.2MB); meanp fp32 [NN,64] aliases (dead after gemm1 / born in agg2)
#define OFF_HB     21001728         // h as bf16 [NN,128] (25.6MB)

#define SCAN_BLOCKS 98  // ceil(100000/1024)

static __device__ __forceinline__ ushort f2bf(float f) {
    unsigned u = __float_as_uint(f);
    return (ushort)((u + 0x7fffu + ((u >> 16) & 1u)) >> 16);
}
static __device__ __forceinline__ float bflo(unsigned u) { return __uint_as_float(u << 16); }
static __device__ __forceinline__ float bfhi(unsigned u) { return __uint_as_float(u & 0xffff0000u); }

// ---------------------------------------------------------------------------
// x (fp32) -> xb (bf16). One float4 per thread.
// ---------------------------------------------------------------------------
__global__ void cvt_kernel(const float* __restrict__ x, ushort* __restrict__ xb) {
    int i = blockIdx.x * 256 + threadIdx.x;          // covers NN*128/4 = 3.2M
    float4 v = ((const float4*)x)[i];
    uint2 o;
    o.x = (unsigned)f2bf(v.x) | ((unsigned)f2bf(v.y) << 16);
    o.y = (unsigned)f2bf(v.z) | ((unsigned)f2bf(v.w) << 16);
    ((uint2*)xb)[i] = o;
}

// ---------------------------------------------------------------------------
// CSR build
// ---------------------------------------------------------------------------
__global__ void hist_kernel(const int* __restrict__ dst, int* __restrict__ deg_cnt) {
    int e = blockIdx.x * 256 + threadIdx.x;
    if (e < NE) atomicAdd(&deg_cnt[dst[e]], 1);
}

__global__ void scan1_kernel(const int* __restrict__ deg_cnt,
                             int* __restrict__ row_ptr,
                             int* __restrict__ bsum) {
    __shared__ int s[256];
    int t = threadIdx.x, b = blockIdx.x;
    int base = b * 1024 + t * 4;
    int v0 = (base + 0 < NN) ? deg_cnt[base + 0] : 0;
    int v1 = (base + 1 < NN) ? deg_cnt[base + 1] : 0;
    int v2 = (base + 2 < NN) ? deg_cnt[base + 2] : 0;
    int v3 = (base + 3 < NN) ? deg_cnt[base + 3] : 0;
    s[t] = v0 + v1 + v2 + v3;
    __syncthreads();
    for (int off = 1; off < 256; off <<= 1) {
        int add = (t >= off) ? s[t - off] : 0;
        __syncthreads();
        s[t] += add;
        __syncthreads();
    }
    int excl = (t == 0) ? 0 : s[t - 1];
    if (base + 0 < NN) row_ptr[base + 0] = excl;
    if (base + 1 < NN) row_ptr[base + 1] = excl + v0;
    if (base + 2 < NN) row_ptr[base + 2] = excl + v0 + v1;
    if (base + 3 < NN) row_ptr[base + 3] = excl + v0 + v1 + v2;
    if (t == 255) bsum[b] = s[255];
}

__global__ void scan2_kernel(int* __restrict__ bsum) {
    __shared__ int s[128];
    int t = threadIdx.x;
    s[t] = (t < SCAN_BLOCKS) ? bsum[t] : 0;
    __syncthreads();
    for (int off = 1; off < 128; off <<= 1) {
        int add = (t >= off) ? s[t - off] : 0;
        __syncthreads();
        s[t] += add;
        __syncthreads();
    }
    if (t < SCAN_BLOCKS) bsum[t] = (t == 0) ? 0 : s[t - 1];
}

__global__ void scan3_kernel(int* __restrict__ row_ptr, const int* __restrict__ bsum) {
    int t = threadIdx.x, b = blockIdx.x;
    int base = b * 1024 + t * 4;
    int add = bsum[b];
#pragma unroll
    for (int i = 0; i < 4; ++i)
        if (base + i < NN) row_ptr[base + i] += add;
}

__global__ void bucket_kernel(const int* __restrict__ src, const int* __restrict__ dst,
                              int* __restrict__ row_ptr, int* __restrict__ es) {
    int e = blockIdx.x * 256 + threadIdx.x;
    if (e >= NE) return;
    int pos = atomicAdd(&row_ptr[dst[e]], 1);
    es[pos] = src[e];
}
// row_ptr[i] now == END of bucket i (start = row_ptr[i-1], 0 for i==0).

// ---------------------------------------------------------------------------
// Layer-1 aggregation over bf16 x: half-wave (32 lanes) per node, lane owns
// 4 channels (uint2 = 4 bf16 = 8B). Unroll-by-4 edges -> up to 8 outstanding
// gathers per wave. Accumulate fp32, write mean fp32.
// ---------------------------------------------------------------------------
__global__ __launch_bounds__(256) void agg1_kernel(const ushort* __restrict__ xb,
                                                   const int* __restrict__ row_end,
                                                   const int* __restrict__ es,
                                                   float* __restrict__ mean) {
    int t = threadIdx.x;
    int node = blockIdx.x * 8 + (t >> 5);
    int l5 = t & 31;
    int start = (node == 0) ? 0 : row_end[node - 1];
    int end = row_end[node];
    const unsigned* xbu = (const unsigned*)xb;   // uint index: row*64 + ch/2
    int co = 2 * l5;                             // uint offset within row
    float a0 = 0.f, a1 = 0.f, a2 = 0.f, a3 = 0.f;
    int e = start;
    for (; e + 4 <= end; e += 4) {
        int s0 = es[e + 0] * 64;
        int s1 = es[e + 1] * 64;
        int s2 = es[e + 2] * 64;
        int s3 = es[e + 3] * 64;
        uint2 u0 = *(const uint2*)&xbu[s0 + co];
        uint2 u1 = *(const uint2*)&xbu[s1 + co];
        uint2 u2 = *(const uint2*)&xbu[s2 + co];
        uint2 u3 = *(const uint2*)&xbu[s3 + co];
        a0 += bflo(u0.x) + bflo(u1.x) + bflo(u2.x) + bflo(u3.x);
        a1 += bfhi(u0.x) + bfhi(u1.x) + bfhi(u2.x) + bfhi(u3.x);
        a2 += bflo(u0.y) + bflo(u1.y) + bflo(u2.y) + bflo(u3.y);
        a3 += bfhi(u0.y) + bfhi(u1.y) + bfhi(u2.y) + bfhi(u3.y);
    }
    for (; e < end; ++e) {
        int s = es[e] * 64;
        uint2 u = *(const uint2*)&xbu[s + co];
        a0 += bflo(u.x); a1 += bfhi(u.x); a2 += bflo(u.y); a3 += bfhi(u.y);
    }
    float inv = 1.0f / fmaxf((float)(end - start), 1.0f);
    float4 o = {a0 * inv, a1 * inv, a2 * inv, a3 * inv};
    *(float4*)&mean[node * 128 + 4 * l5] = o;
}

// ---------------------------------------------------------------------------
// Layer-2 aggregation over bf16 pl=[NN,64] (12.8MB, ~L2-resident):
// half-wave per node, lane owns 2 channels (uint = 2 bf16). Writes meanp fp32.
// ---------------------------------------------------------------------------
__global__ __launch_bounds__(256) void agg2_kernel(const ushort* __restrict__ pb,
                                                   const int* __restrict__ row_end,
                                                   const int* __restrict__ es,
                                                   float* __restrict__ meanp) {
    int t = threadIdx.x;
    int node = blockIdx.x * 8 + (t >> 5);
    int l5 = t & 31;
    int start = (node == 0) ? 0 : row_end[node - 1];
    int end = row_end[node];
    const unsigned* pbu = (const unsigned*)pb;   // uint index: row*32 + ch/2
    float a0 = 0.f, a1 = 0.f;
    int e = start;
    for (; e + 4 <= end; e += 4) {
        unsigned u0 = pbu[es[e + 0] * 32 + l5];
        unsigned u1 = pbu[es[e + 1] * 32 + l5];
        unsigned u2 = pbu[es[e + 2] * 32 + l5];
        unsigned u3 = pbu[es[e + 3] * 32 + l5];
        a0 += bflo(u0) + bflo(u1) + bflo(u2) + bflo(u3);
        a1 += bfhi(u0) + bfhi(u1) + bfhi(u2) + bfhi(u3);
    }
    for (; e < end; ++e) {
        unsigned u = pbu[es[e] * 32 + l5];
        a0 += bflo(u); a1 += bfhi(u);
    }
    float inv = 1.0f / fmaxf((float)(end - start), 1.0f);
    float2 o = {a0 * inv, a1 * inv};
    *(float2*)&meanp[node * 64 + 2 * l5] = o;
}

// ---------------------------------------------------------------------------
// GEMM layer 1 (fused): h = relu(mean@W1l + x@W1r + b1); hb = bf16(h);
// pb = bf16(h @ W2l). 256 thr / 32 nodes per block; wave w owns nodes 8w..8w+7
// (LDS rows are wave-private -> no second barrier needed for the pl stage).
// ---------------------------------------------------------------------------
__global__ __launch_bounds__(256) void gemm1_kernel(const float* __restrict__ mean,
                                                    const float* __restrict__ x,
                                                    const float* __restrict__ W1l,
                                                    const float* __restrict__ W1r,
                                                    const float* __restrict__ b1,
                                                    const float* __restrict__ W2l,
                                                    ushort* __restrict__ hb,
                                                    ushort* __restrict__ pb) {
    __shared__ float ms[32 * 128];
    __shared__ float xs[32 * 128];
    int t = threadIdx.x;
    long long node0 = (long long)blockIdx.x * 32;
    const float4* mg = (const float4*)(mean + node0 * 128);
    const float4* xg = (const float4*)(x + node0 * 128);
#pragma unroll
    for (int i = 0; i < 4; ++i) {
        ((float4*)ms)[t + 256 * i] = mg[t + 256 * i];
        ((float4*)xs)[t + 256 * i] = xg[t + 256 * i];
    }
    __syncthreads();

    int w = t >> 6;
    int l = t & 63;
    int nbase = w * 8;
    int c = 2 * l;
    float2 bias = *(const float2*)&b1[c];
    float acc0[8], acc1[8];
#pragma unroll
    for (int n = 0; n < 8; ++n) { acc0[n] = bias.x; acc1[n] = bias.y; }

    for (int k4 = 0; k4 < 32; ++k4) {
        float2 wl[4], wr[4];
#pragma unroll
        for (int kk = 0; kk < 4; ++kk) {
            wl[kk] = *(const float2*)&W1l[(4 * k4 + kk) * 128 + c];
            wr[kk] = *(const float2*)&W1r[(4 * k4 + kk) * 128 + c];
        }
#pragma unroll
        for (int n = 0; n < 8; ++n) {
            const float4 mv = *(const float4*)&ms[(nbase + n) * 128 + 4 * k4];
            const float4 xv = *(const float4*)&xs[(nbase + n) * 128 + 4 * k4];
            acc0[n] += mv.x * wl[0].x + mv.y * wl[1].x + mv.z * wl[2].x + mv.w * wl[3].x
                     + xv.x * wr[0].x + xv.y * wr[1].x + xv.z * wr[2].x + xv.w * wr[3].x;
            acc1[n] += mv.x * wl[0].y + mv.y * wl[1].y + mv.z * wl[2].y + mv.w * wl[3].y
                     + xv.x * wr[0].y + xv.y * wr[1].y + xv.z * wr[2].y + xv.w * wr[3].y;
        }
    }

    // Epilogue: relu, write hb (bf16), park fp32 h rows back in xs (wave-private).
    unsigned* hbu = (unsigned*)hb;
#pragma unroll
    for (int n = 0; n < 8; ++n) {
        float h0 = fmaxf(acc0[n], 0.0f);
        float h1 = fmaxf(acc1[n], 0.0f);
        long long row = node0 + nbase + n;
        hbu[row * 64 + l] = (unsigned)f2bf(h0) | ((unsigned)f2bf(h1) << 16);
        *(float2*)&xs[(nbase + n) * 128 + c] = make_float2(h0, h1);
    }

    // pl = h @ W2l  (lane l -> out channel l of 64)
    float p[8];
#pragma unroll
    for (int n = 0; n < 8; ++n) p[n] = 0.0f;
    for (int k4 = 0; k4 < 32; ++k4) {
        float wv[4];
#pragma unroll
        for (int kk = 0; kk < 4; ++kk) wv[kk] = W2l[(4 * k4 + kk) * 64 + l];
#pragma unroll
        for (int n = 0; n < 8; ++n) {
            const float4 hv = *(const float4*)&xs[(nbase + n) * 128 + 4 * k4];
            p[n] += hv.x * wv[0] + hv.y * wv[1] + hv.z * wv[2] + hv.w * wv[3];
        }
    }
#pragma unroll
    for (int n = 0; n < 8; ++n)
        pb[(node0 + nbase + n) * 64 + l] = f2bf(p[n]);
}

// ---------------------------------------------------------------------------
// GEMM layer 2: out = meanp + h@W2r + b2  (h read back as bf16, unpacked to LDS)
// ---------------------------------------------------------------------------
__global__ __launch_bounds__(256) void gemm2_kernel(const float* __restrict__ meanp,
                                                    const ushort* __restrict__ hb,
                                                    const float* __restrict__ W2r,
                                                    const float* __restrict__ b2,
                                                    float* __restrict__ out) {
    __shared__ float hs[32 * 128];
    int t = threadIdx.x;
    long long node0 = (long long)blockIdx.x * 32;
    const uint4* hg = (const uint4*)(hb + node0 * 128);  // 32*128 ushorts = 1024 uint4
#pragma unroll
    for (int i = 0; i < 4; ++i) {
        uint4 u = hg[t + 256 * i];
        int base = 8 * (t + 256 * i);
        hs[base + 0] = bflo(u.x); hs[base + 1] = bfhi(u.x);
        hs[base + 2] = bflo(u.y); hs[base + 3] = bfhi(u.y);
        hs[base + 4] = bflo(u.z); hs[base + 5] = bfhi(u.z);
        hs[base + 6] = bflo(u.w); hs[base + 7] = bfhi(u.w);
    }
    __syncthreads();

    int w = t >> 6;
    int l = t & 63;
    int nbase = w * 8;
    float acc[8];
    float bias = b2[l];
#pragma unroll
    for (int n = 0; n < 8; ++n)
        acc[n] = bias + meanp[(node0 + nbase + n) * 64 + l];

    for (int k4 = 0; k4 < 32; ++k4) {
        float wv[4];
#pragma unroll
        for (int kk = 0; kk < 4; ++kk) wv[kk] = W2r[(4 * k4 + kk) * 64 + l];
#pragma unroll
        for (int n = 0; n < 8; ++n) {
            const float4 hv = *(const float4*)&hs[(nbase + n) * 128 + 4 * k4];
            acc[n] += hv.x * wv[0] + hv.y * wv[1] + hv.z * wv[2] + hv.w * wv[3];
        }
    }
#pragma unroll
    for (int n = 0; n < 8; ++n)
        out[(node0 + nbase + n) * 64 + l] = acc[n];
}

extern "C" void kernel_launch(void* const* d_in, const int* in_sizes, int n_in,
                              void* d_out, int out_size, void* d_ws, size_t ws_size,
                              hipStream_t stream) {
    const float* x   = (const float*)d_in[0];
    const int*   ei  = (const int*)d_in[1];
    const float* W1l = (const float*)d_in[2];
    const float* W1r = (const float*)d_in[3];
    const float* b1  = (const float*)d_in[4];
    const float* W2l = (const float*)d_in[5];
    const float* W2r = (const float*)d_in[6];
    const float* b2  = (const float*)d_in[7];

    const int* src = ei;
    const int* dst = ei + NE;

    int*    ws_i    = (int*)d_ws;
    int*    deg_cnt = ws_i + OFF_DEGCNT;
    int*    row_ptr = ws_i + OFF_ROWPTR;
    int*    bsum    = ws_i + OFF_BSUM;
    int*    es      = ws_i + OFF_ES;
    ushort* xb      = (ushort*)(ws_i + OFF_XB);
    ushort* pb      = (ushort*)(ws_i + OFF_XB);   // aliases xb (disjoint lifetime)
    float*  mean1   = (float*)(ws_i + OFF_MEAN);
    float*  meanp   = (float*)(ws_i + OFF_MEAN);  // aliases mean1 (disjoint lifetime)
    ushort* hb      = (ushort*)(ws_i + OFF_HB);

    // CSR build + bf16 conversion of x
    hipMemsetAsync(deg_cnt, 0, 100352 * sizeof(int), stream);
    cvt_kernel<<<12500, 256, 0, stream>>>(x, xb);
    hist_kernel<<<(NE + 255) / 256, 256, 0, stream>>>(dst, deg_cnt);
    scan1_kernel<<<SCAN_BLOCKS, 256, 0, stream>>>(deg_cnt, row_ptr, bsum);
    scan2_kernel<<<1, 128, 0, stream>>>(bsum);
    scan3_kernel<<<SCAN_BLOCKS, 256, 0, stream>>>(row_ptr, bsum);
    bucket_kernel<<<(NE + 255) / 256, 256, 0, stream>>>(src, dst, row_ptr, es);

    // Layer 1
    agg1_kernel<<<NN / 8, 256, 0, stream>>>(xb, row_ptr, es, mean1);
    gemm1_kernel<<<NN / 32, 256, 0, stream>>>(mean1, x, W1l, W1r, b1, W2l, hb, pb);

    // Layer 2 (aggregation commuted past W2l)
    agg2_kernel<<<NN / 8, 256, 0, stream>>>(pb, row_ptr, es, meanp);
    gemm2_kernel<<<NN / 32, 256, 0, stream>>>(meanp, hb, W2r, b2, (float*)d_out);
}

// Round 4
// 449.365 us; speedup vs baseline: 4.7010x; 1.3814x over previous
//
#include <hip/hip_runtime.h>

#define NN 100000
#define NE 1600000

// Workspace layout in 4-byte units (total 24,247,808 uints = 97.0 MB):
#define OFF_DEGCNT 0
#define OFF_ROWPTR 100352
#define OFF_BSUM   200704
#define OFF_ES     201728
#define OFF_XB     1801728            // x bf16 [100096,128]
#define OFF_MEANB  8207872            // mean bf16 [100096,128]; meanp fp32 [100096,64] aliases (disjoint lifetime)
#define OFF_HB     14614016           // h bf16 [100096,128]
#define OFF_PB     21020160           // pl bf16 [100096,64]
#define OFF_W1LP   24223232           // packed weights bf16: 8192+8192+4096+4096 uints
#define OFF_W1RP   (24223232 + 8192)
#define OFF_W2LP   (24223232 + 16384)
#define OFF_W2RP   (24223232 + 20480)

#define SCAN_BLOCKS 98  // ceil(100000/1024)

typedef __bf16 bf16x8 __attribute__((ext_vector_type(8)));
typedef float f32x4 __attribute__((ext_vector_type(4)));

static __device__ __forceinline__ ushort f2bf(float f) {
    unsigned u = __float_as_uint(f);
    return (ushort)((u + 0x7fffu + ((u >> 16) & 1u)) >> 16);
}
static __device__ __forceinline__ float bflo(unsigned u) { return __uint_as_float(u << 16); }
static __device__ __forceinline__ float bfhi(unsigned u) { return __uint_as_float(u & 0xffff0000u); }

// ---------------------------------------------------------------------------
// x (fp32) -> xb (bf16). One float4 per thread.
// ---------------------------------------------------------------------------
__global__ void cvt_kernel(const float* __restrict__ x, ushort* __restrict__ xb) {
    int i = blockIdx.x * 256 + threadIdx.x;  // covers NN*128/4 = 3.2M
    float4 v = ((const float4*)x)[i];
    uint2 o;
    o.x = (unsigned)f2bf(v.x) | ((unsigned)f2bf(v.y) << 16);
    o.y = (unsigned)f2bf(v.z) | ((unsigned)f2bf(v.w) << 16);
    ((uint2*)xb)[i] = o;
}

// ---------------------------------------------------------------------------
// Pack all 4 weight matrices fp32 -> bf16 MFMA B-frag layout:
// frag f=(ktile*NT+ntile): out[(f*64+lane)*8 + j] = bf16(W[(ktile*32+(lane>>4)*8+j)*N + ntile*16+(lane&15)])
// Blocks 0-7: W1l(N=128), 8-15: W1r(128), 16-19: W2l(64), 20-23: W2r(64).
// ---------------------------------------------------------------------------
__global__ void pack_kernel(const float* __restrict__ W1l, const float* __restrict__ W1r,
                            const float* __restrict__ W2l, const float* __restrict__ W2r,
                            ushort* __restrict__ w1lp, ushort* __restrict__ w1rp,
                            ushort* __restrict__ w2lp, ushort* __restrict__ w2rp) {
    int blk = blockIdx.x;
    const float* W;
    ushort* out;
    int N, frag0;
    if (blk < 8)       { W = W1l; out = w1lp; N = 128; frag0 = blk * 4; }
    else if (blk < 16) { W = W1r; out = w1rp; N = 128; frag0 = (blk - 8) * 4; }
    else if (blk < 20) { W = W2l; out = w2lp; N = 64;  frag0 = (blk - 16) * 4; }
    else               { W = W2r; out = w2rp; N = 64;  frag0 = (blk - 20) * 4; }
    int lane = threadIdx.x & 63;
    int frag = frag0 + (threadIdx.x >> 6);
    int NT = N >> 4;
    int ktile = frag / NT, ntile = frag - ktile * NT;
    int k = ktile * 32 + (lane >> 4) * 8;
    int n = ntile * 16 + (lane & 15);
    ushort tmp[8];
#pragma unroll
    for (int j = 0; j < 8; ++j) tmp[j] = f2bf(W[(k + j) * N + n]);
    uint4 o;
    o.x = (unsigned)tmp[0] | ((unsigned)tmp[1] << 16);
    o.y = (unsigned)tmp[2] | ((unsigned)tmp[3] << 16);
    o.z = (unsigned)tmp[4] | ((unsigned)tmp[5] << 16);
    o.w = (unsigned)tmp[6] | ((unsigned)tmp[7] << 16);
    *(uint4*)&out[(frag * 64 + lane) * 8] = o;
}

// ---------------------------------------------------------------------------
// CSR build
// ---------------------------------------------------------------------------
__global__ void hist_kernel(const int* __restrict__ dst, int* __restrict__ deg_cnt) {
    int e = blockIdx.x * 256 + threadIdx.x;
    if (e < NE) atomicAdd(&deg_cnt[dst[e]], 1);
}

__global__ void scan1_kernel(const int* __restrict__ deg_cnt,
                             int* __restrict__ row_ptr,
                             int* __restrict__ bsum) {
    __shared__ int s[256];
    int t = threadIdx.x, b = blockIdx.x;
    int base = b * 1024 + t * 4;
    int v0 = (base + 0 < NN) ? deg_cnt[base + 0] : 0;
    int v1 = (base + 1 < NN) ? deg_cnt[base + 1] : 0;
    int v2 = (base + 2 < NN) ? deg_cnt[base + 2] : 0;
    int v3 = (base + 3 < NN) ? deg_cnt[base + 3] : 0;
    s[t] = v0 + v1 + v2 + v3;
    __syncthreads();
    for (int off = 1; off < 256; off <<= 1) {
        int add = (t >= off) ? s[t - off] : 0;
        __syncthreads();
        s[t] += add;
        __syncthreads();
    }
    int excl = (t == 0) ? 0 : s[t - 1];
    if (base + 0 < NN) row_ptr[base + 0] = excl;
    if (base + 1 < NN) row_ptr[base + 1] = excl + v0;
    if (base + 2 < NN) row_ptr[base + 2] = excl + v0 + v1;
    if (base + 3 < NN) row_ptr[base + 3] = excl + v0 + v1 + v2;
    if (t == 255) bsum[b] = s[255];
}

__global__ void scan2_kernel(int* __restrict__ bsum) {
    __shared__ int s[128];
    int t = threadIdx.x;
    s[t] = (t < SCAN_BLOCKS) ? bsum[t] : 0;
    __syncthreads();
    for (int off = 1; off < 128; off <<= 1) {
        int add = (t >= off) ? s[t - off] : 0;
        __syncthreads();
        s[t] += add;
        __syncthreads();
    }
    if (t < SCAN_BLOCKS) bsum[t] = (t == 0) ? 0 : s[t - 1];
}

__global__ void scan3_kernel(int* __restrict__ row_ptr, const int* __restrict__ bsum) {
    int t = threadIdx.x, b = blockIdx.x;
    int base = b * 1024 + t * 4;
    int add = bsum[b];
#pragma unroll
    for (int i = 0; i < 4; ++i)
        if (base + i < NN) row_ptr[base + i] += add;
}

__global__ void bucket_kernel(const int* __restrict__ src, const int* __restrict__ dst,
                              int* __restrict__ row_ptr, int* __restrict__ es) {
    int e = blockIdx.x * 256 + threadIdx.x;
    if (e >= NE) return;
    int pos = atomicAdd(&row_ptr[dst[e]], 1);
    es[pos] = src[e];
}
// row_ptr[i] now == END of bucket i (start = row_ptr[i-1], 0 for i==0).

// ---------------------------------------------------------------------------
// Layer-1 aggregation over bf16 x: half-wave per node, lane owns 4 channels.
// Accumulate fp32, write mean as bf16 (uint2 per lane).
// ---------------------------------------------------------------------------
__global__ __launch_bounds__(256) void agg1_kernel(const ushort* __restrict__ xb,
                                                   const int* __restrict__ row_end,
                                                   const int* __restrict__ es,
                                                   ushort* __restrict__ meanb) {
    int t = threadIdx.x;
    int node = blockIdx.x * 8 + (t >> 5);
    int l5 = t & 31;
    int start = (node == 0) ? 0 : row_end[node - 1];
    int end = row_end[node];
    const unsigned* xbu = (const unsigned*)xb;
    int co = 2 * l5;
    float a0 = 0.f, a1 = 0.f, a2 = 0.f, a3 = 0.f;
    int e = start;
    for (; e + 4 <= end; e += 4) {
        int s0 = es[e + 0] * 64;
        int s1 = es[e + 1] * 64;
        int s2 = es[e + 2] * 64;
        int s3 = es[e + 3] * 64;
        uint2 u0 = *(const uint2*)&xbu[s0 + co];
        uint2 u1 = *(const uint2*)&xbu[s1 + co];
        uint2 u2 = *(const uint2*)&xbu[s2 + co];
        uint2 u3 = *(const uint2*)&xbu[s3 + co];
        a0 += bflo(u0.x) + bflo(u1.x) + bflo(u2.x) + bflo(u3.x);
        a1 += bfhi(u0.x) + bfhi(u1.x) + bfhi(u2.x) + bfhi(u3.x);
        a2 += bflo(u0.y) + bflo(u1.y) + bflo(u2.y) + bflo(u3.y);
        a3 += bfhi(u0.y) + bfhi(u1.y) + bfhi(u2.y) + bfhi(u3.y);
    }
    for (; e < end; ++e) {
        int s = es[e] * 64;
        uint2 u = *(const uint2*)&xbu[s + co];
        a0 += bflo(u.x); a1 += bfhi(u.x); a2 += bflo(u.y); a3 += bfhi(u.y);
    }
    float inv = 1.0f / fmaxf((float)(end - start), 1.0f);
    uint2 o;
    o.x = (unsigned)f2bf(a0 * inv) | ((unsigned)f2bf(a1 * inv) << 16);
    o.y = (unsigned)f2bf(a2 * inv) | ((unsigned)f2bf(a3 * inv) << 16);
    *(uint2*)&((unsigned*)meanb)[node * 64 + co] = o;
}

// ---------------------------------------------------------------------------
// Layer-2 aggregation over bf16 pl=[NN,64]: half-wave per node, lane owns
// 2 channels. Writes meanp fp32.
// ---------------------------------------------------------------------------
__global__ __launch_bounds__(256) void agg2_kernel(const ushort* __restrict__ pb,
                                                   const int* __restrict__ row_end,
                                                   const int* __restrict__ es,
                                                   float* __restrict__ meanp) {
    int t = threadIdx.x;
    int node = blockIdx.x * 8 + (t >> 5);
    int l5 = t & 31;
    int start = (node == 0) ? 0 : row_end[node - 1];
    int end = row_end[node];
    const unsigned* pbu = (const unsigned*)pb;
    float a0 = 0.f, a1 = 0.f;
    int e = start;
    for (; e + 4 <= end; e += 4) {
        unsigned u0 = pbu[es[e + 0] * 32 + l5];
        unsigned u1 = pbu[es[e + 1] * 32 + l5];
        unsigned u2 = pbu[es[e + 2] * 32 + l5];
        unsigned u3 = pbu[es[e + 3] * 32 + l5];
        a0 += bflo(u0) + bflo(u1) + bflo(u2) + bflo(u3);
        a1 += bfhi(u0) + bfhi(u1) + bfhi(u2) + bfhi(u3);
    }
    for (; e < end; ++e) {
        unsigned u = pbu[es[e] * 32 + l5];
        a0 += bflo(u); a1 += bfhi(u);
    }
    float inv = 1.0f / fmaxf((float)(end - start), 1.0f);
    float2 o = {a0 * inv, a1 * inv};
    *(float2*)&meanp[node * 64 + 2 * l5] = o;
}

// ---------------------------------------------------------------------------
// GEMM1 (MFMA): h = relu(mean@W1l + x@W1r + b1); hb = bf16(h); pb = bf16(h@W2l).
// Block = 256 thr (4 waves), 64 nodes. Wave w owns rows w*16..w*16+15.
// A tiles staged in LDS, row stride 136 ushorts (272B) for conflict-free b128.
// B-frags are coalesced 16B global loads from packed weights (L2-resident).
// ---------------------------------------------------------------------------
__global__ __launch_bounds__(256) void gemm1_kernel(const ushort* __restrict__ meanb,
                                                    const ushort* __restrict__ xb,
                                                    const ushort* __restrict__ w1lp,
                                                    const ushort* __restrict__ w1rp,
                                                    const float* __restrict__ b1,
                                                    const ushort* __restrict__ w2lp,
                                                    ushort* __restrict__ hb,
                                                    ushort* __restrict__ pb) {
    __shared__ ushort As[64 * 136];
    int t = threadIdx.x;
    int node0 = blockIdx.x * 64;
    int w = t >> 6, l = t & 63;
    int lrow = w * 16 + (l & 15);
    int lkq = (l >> 4) * 8;
    int cq = l & 15, rq = (l >> 4) * 4;

    f32x4 acc[8];
#pragma unroll
    for (int i = 0; i < 8; ++i) acc[i] = (f32x4){0.f, 0.f, 0.f, 0.f};

    // ---- phase 1: mean @ W1l ----
    {
        const uint4* g = (const uint4*)(meanb + (size_t)node0 * 128);
#pragma unroll
        for (int i = 0; i < 4; ++i) {
            int chunk = t + 256 * i;
            *(uint4*)&As[(chunk >> 4) * 136 + (chunk & 15) * 8] = g[chunk];
        }
    }
    __syncthreads();
#pragma unroll
    for (int kt = 0; kt < 4; ++kt) {
        bf16x8 a = *(const bf16x8*)&As[lrow * 136 + kt * 32 + lkq];
        const bf16x8* bp = (const bf16x8*)w1lp + (kt * 8) * 64 + l;
#pragma unroll
        for (int nt = 0; nt < 8; ++nt)
            acc[nt] = __builtin_amdgcn_mfma_f32_16x16x32_bf16(a, bp[nt * 64], acc[nt], 0, 0, 0);
    }
    __syncthreads();

    // ---- phase 2: x @ W1r ----
    {
        const uint4* g = (const uint4*)(xb + (size_t)node0 * 128);
#pragma unroll
        for (int i = 0; i < 4; ++i) {
            int chunk = t + 256 * i;
            *(uint4*)&As[(chunk >> 4) * 136 + (chunk & 15) * 8] = g[chunk];
        }
    }
    __syncthreads();
#pragma unroll
    for (int kt = 0; kt < 4; ++kt) {
        bf16x8 a = *(const bf16x8*)&As[lrow * 136 + kt * 32 + lkq];
        const bf16x8* bp = (const bf16x8*)w1rp + (kt * 8) * 64 + l;
#pragma unroll
        for (int nt = 0; nt < 8; ++nt)
            acc[nt] = __builtin_amdgcn_mfma_f32_16x16x32_bf16(a, bp[nt * 64], acc[nt], 0, 0, 0);
    }
    __syncthreads();

    // ---- epilogue: relu + bias, park h (bf16) in LDS ----
#pragma unroll
    for (int nt = 0; nt < 8; ++nt) {
        int n = nt * 16 + cq;
        float bias = b1[n];
#pragma unroll
        for (int r = 0; r < 4; ++r) {
            float hv = fmaxf(acc[nt][r] + bias, 0.0f);
            As[(w * 16 + rq + r) * 136 + n] = f2bf(hv);
        }
    }
    __syncthreads();

    // ---- stream hb out (coalesced) ----
    {
        uint4* g = (uint4*)(hb + (size_t)node0 * 128);
#pragma unroll
        for (int i = 0; i < 4; ++i) {
            int chunk = t + 256 * i;
            if (node0 + (chunk >> 4) < NN)
                g[chunk] = *(const uint4*)&As[(chunk >> 4) * 136 + (chunk & 15) * 8];
        }
    }

    // ---- pl = h @ W2l ----
    f32x4 acc2[4];
#pragma unroll
    for (int i = 0; i < 4; ++i) acc2[i] = (f32x4){0.f, 0.f, 0.f, 0.f};
#pragma unroll
    for (int kt = 0; kt < 4; ++kt) {
        bf16x8 a = *(const bf16x8*)&As[lrow * 136 + kt * 32 + lkq];
        const bf16x8* bp = (const bf16x8*)w2lp + (kt * 4) * 64 + l;
#pragma unroll
        for (int nt = 0; nt < 4; ++nt)
            acc2[nt] = __builtin_amdgcn_mfma_f32_16x16x32_bf16(a, bp[nt * 64], acc2[nt], 0, 0, 0);
    }
    __syncthreads();

    // ---- park pb (bf16) in LDS, stream out coalesced ----
#pragma unroll
    for (int nt = 0; nt < 4; ++nt)
#pragma unroll
        for (int r = 0; r < 4; ++r)
            As[(w * 16 + rq + r) * 136 + nt * 16 + cq] = f2bf(acc2[nt][r]);
    __syncthreads();
    {
        uint4* g = (uint4*)(pb + (size_t)node0 * 64);
#pragma unroll
        for (int i = 0; i < 2; ++i) {
            int chunk = t + 256 * i;
            if (node0 + (chunk >> 3) < NN)
                g[chunk] = *(const uint4*)&As[(chunk >> 3) * 136 + (chunk & 7) * 8];
        }
    }
}

// ---------------------------------------------------------------------------
// GEMM2 (MFMA): out = meanp + hb@W2r + b2.
// ---------------------------------------------------------------------------
__global__ __launch_bounds__(256) void gemm2_kernel(const float* __restrict__ meanp,
                                                    const ushort* __restrict__ hb,
                                                    const ushort* __restrict__ w2rp,
                                                    const float* __restrict__ b2,
                                                    float* __restrict__ out) {
    __shared__ ushort As[64 * 136];
    int t = threadIdx.x;
    int node0 = blockIdx.x * 64;
    int w = t >> 6, l = t & 63;
    int lrow = w * 16 + (l & 15);
    int lkq = (l >> 4) * 8;
    int cq = l & 15, rq = (l >> 4) * 4;

    {
        const uint4* g = (const uint4*)(hb + (size_t)node0 * 128);
#pragma unroll
        for (int i = 0; i < 4; ++i) {
            int chunk = t + 256 * i;
            *(uint4*)&As[(chunk >> 4) * 136 + (chunk & 15) * 8] = g[chunk];
        }
    }
    __syncthreads();

    f32x4 acc[4];
#pragma unroll
    for (int i = 0; i < 4; ++i) acc[i] = (f32x4){0.f, 0.f, 0.f, 0.f};
#pragma unroll
    for (int kt = 0; kt < 4; ++kt) {
        bf16x8 a = *(const bf16x8*)&As[lrow * 136 + kt * 32 + lkq];
        const bf16x8* bp = (const bf16x8*)w2rp + (kt * 4) * 64 + l;
#pragma unroll
        for (int nt = 0; nt < 4; ++nt)
            acc[nt] = __builtin_amdgcn_mfma_f32_16x16x32_bf16(a, bp[nt * 64], acc[nt], 0, 0, 0);
    }

#pragma unroll
    for (int nt = 0; nt < 4; ++nt) {
        int n = nt * 16 + cq;
        float bias = b2[n];
#pragma unroll
        for (int r = 0; r < 4; ++r) {
            int row = node0 + w * 16 + rq + r;
            if (row < NN)
                out[(size_t)row * 64 + n] = acc[nt][r] + bias + meanp[(size_t)row * 64 + n];
        }
    }
}

extern "C" void kernel_launch(void* const* d_in, const int* in_sizes, int n_in,
                              void* d_out, int out_size, void* d_ws, size_t ws_size,
                              hipStream_t stream) {
    const float* x   = (const float*)d_in[0];
    const int*   ei  = (const int*)d_in[1];
    const float* W1l = (const float*)d_in[2];
    const float* W1r = (const float*)d_in[3];
    const float* b1  = (const float*)d_in[4];
    const float* W2l = (const float*)d_in[5];
    const float* W2r = (const float*)d_in[6];
    const float* b2  = (const float*)d_in[7];

    const int* src = ei;
    const int* dst = ei + NE;

    int*    ws_i    = (int*)d_ws;
    int*    deg_cnt = ws_i + OFF_DEGCNT;
    int*    row_ptr = ws_i + OFF_ROWPTR;
    int*    bsum    = ws_i + OFF_BSUM;
    int*    es      = ws_i + OFF_ES;
    ushort* xb      = (ushort*)(ws_i + OFF_XB);
    ushort* meanb   = (ushort*)(ws_i + OFF_MEANB);
    float*  meanp   = (float*)(ws_i + OFF_MEANB);  // aliases meanb (disjoint lifetime)
    ushort* hb      = (ushort*)(ws_i + OFF_HB);
    ushort* pb      = (ushort*)(ws_i + OFF_PB);
    ushort* w1lp    = (ushort*)(ws_i + OFF_W1LP);
    ushort* w1rp    = (ushort*)(ws_i + OFF_W1RP);
    ushort* w2lp    = (ushort*)(ws_i + OFF_W2LP);
    ushort* w2rp    = (ushort*)(ws_i + OFF_W2RP);

    // CSR build + conversions + weight packing
    hipMemsetAsync(deg_cnt, 0, 100352 * sizeof(int), stream);
    cvt_kernel<<<12500, 256, 0, stream>>>(x, xb);
    pack_kernel<<<24, 256, 0, stream>>>(W1l, W1r, W2l, W2r, w1lp, w1rp, w2lp, w2rp);
    hist_kernel<<<(NE + 255) / 256, 256, 0, stream>>>(dst, deg_cnt);
    scan1_kernel<<<SCAN_BLOCKS, 256, 0, stream>>>(deg_cnt, row_ptr, bsum);
    scan2_kernel<<<1, 128, 0, stream>>>(bsum);
    scan3_kernel<<<SCAN_BLOCKS, 256, 0, stream>>>(row_ptr, bsum);
    bucket_kernel<<<(NE + 255) / 256, 256, 0, stream>>>(src, dst, row_ptr, es);

    // Layer 1
    agg1_kernel<<<NN / 8, 256, 0, stream>>>(xb, row_ptr, es, meanb);
    gemm1_kernel<<<(NN + 63) / 64, 256, 0, stream>>>(meanb, xb, w1lp, w1rp, b1, w2lp, hb, pb);

    // Layer 2 (aggregation commuted past W2l)
    agg2_kernel<<<NN / 8, 256, 0, stream>>>(pb, row_ptr, es, meanp);
    gemm2_kernel<<<(NN + 63) / 64, 256, 0, stream>>>(meanp, hb, w2rp, b2, (float*)d_out);
}